// Round 7
// baseline (350.564 us; speedup 1.0000x reference)
//
#include <hip/hip_runtime.h>

typedef __attribute__((ext_vector_type(8))) short bf16x8;
typedef __attribute__((ext_vector_type(4))) float f32x4;

#define Hh   16
#define Ll   680
#define Cc   1024
#define Bb   16
#define NSEG 10
#define LPAD 720   // padded per-segment V length (each segment start 8-aligned)

__device__ __forceinline__ unsigned short f32_bf16(float f) {
  union { float f; unsigned int u; } x; x.f = f;
  unsigned int r = x.u + 0x7FFFu + ((x.u >> 16) & 1u);   // RNE
  return (unsigned short)(r >> 16);
}
__device__ __forceinline__ float bf16_f32(unsigned short u) {
  union { unsigned int u; float f; } x; x.u = ((unsigned int)u) << 16;
  return x.f;
}

__device__ __forceinline__ void async_copy16(const unsigned short* g, unsigned short* l) {
  __builtin_amdgcn_global_load_lds(
      (const __attribute__((address_space(1))) unsigned int*)g,
      (__attribute__((address_space(3))) unsigned int*)l, 16, 0, 0);
}

// segment tables (patch_nums are compile-time constants)
__device__ __constant__ int c_start2[11] = {0,1,5,14,30,55,91,155,255,424,680};
__device__ __constant__ int c_ps[NSEG]   = {0,8,16,32,48,80,120,184,288,464};
__device__ __constant__ int c_seg[16]    = {0,1,2,3,4,5,6,7,7,8,8,8,9,9,9,9};
__device__ __constant__ int c_tile0[16]  = {0,0,0,0,0,0,0,0,4,0,4,8,0,4,8,12};
__device__ __constant__ int c_len[NSEG]  = {1,4,9,16,25,36,64,100,169,256};

// compile-time l -> padded-l table (kills the per-element segment search)
struct PlTab { unsigned short v[Ll]; };
constexpr PlTab make_pl() {
  PlTab t{};
  int starts[11] = {0,1,5,14,30,55,91,155,255,424,680};
  int ps[10]     = {0,8,16,32,48,80,120,184,288,464};
  for (int s = 0; s < 10; ++s)
    for (int l = starts[s]; l < starts[s + 1]; ++l)
      t.v[l] = (unsigned short)(l - starts[s] + ps[s]);
  return t;
}
__device__ __constant__ PlTab c_plt = make_pl();

#define BARRIER __builtin_amdgcn_s_barrier()
#define LGKM0   asm volatile("s_waitcnt lgkmcnt(0)" ::: "memory")
#define PRIO1   __builtin_amdgcn_s_setprio(1)
#define PRIO0   __builtin_amdgcn_s_setprio(0)
#define SCHED0  __builtin_amdgcn_sched_barrier(0)

// ---------------- elementwise f32 -> bf16 cast ----------------
__global__ __launch_bounds__(256) void conv_kernel(const float* __restrict__ src,
                                                   unsigned short* __restrict__ dst, int n) {
  int i = (blockIdx.x * 256 + threadIdx.x) * 4;
  if (i + 3 < n) {
    float4 v = *reinterpret_cast<const float4*>(src + i);
    ushort4 o;
    o.x = f32_bf16(v.x); o.y = f32_bf16(v.y); o.z = f32_bf16(v.z); o.w = f32_bf16(v.w);
    *reinterpret_cast<ushort4*>(dst + i) = o;
  }
}

// ---------------- QKV GEMM v6: 256x256 tile, 8-phase, RACE-FIXED vmcnt ----------------
// v5 bug: vmcnt placed AFTER the barrier (consumer side) -> wave X's vmcnt says nothing
// about wave Y's loads -> read of in-flight LDS -> NaN. Correct invariant (R1-R4, m201):
// stage -> vmcnt -> BARRIER -> read. vmcnt(4) now sits at END of p3/p7 (producer side).
// Steady state per wave at p3-end: [B(2i+1)x4, A(2i+1)x4, B(2i+2)x4] -> vmcnt(4) retires
// exactly the 8 that p4 reads. Never drains to 0; loads span 4-6 phases.
__global__ __launch_bounds__(512, 2) void gemm_qkv(const unsigned short* __restrict__ A,
                                                   const unsigned short* __restrict__ Bm,
                                                   const float* __restrict__ qb,
                                                   const float* __restrict__ vb,
                                                   unsigned short* __restrict__ qn,
                                                   unsigned short* __restrict__ kn,
                                                   unsigned short* __restrict__ vtb) {
  // A buf b at b*16384 shorts; B buf b at 32768 + b*16384. Total 65536 shorts = 128KB.
  __shared__ __align__(16) unsigned short lds[65536];
  const int t = threadIdx.x;
  const int lane = t & 63, w = t >> 6;
  const int col = lane & 15, quad = lane >> 4;
  const int wm2 = w >> 2;                 // M half (0/1) -> rows wm2*128..+127
  const int wn2 = w & 3;                  // N quarter    -> cols wn2*64..+63
  const int m0 = blockIdx.y * 256, n0 = blockIdx.x * 256;

  // stage one A half-tile (128 rows x 64 k): 2 loads/thread; rows clamped for tail tile
  auto stageA = [&](int buf, int half, int kt) {
    int kc = (kt > 15 ? 15 : kt) * 64;
#pragma unroll
    for (int ii = 0; ii < 2; ++ii) {
      int c = ii * 512 + t;
      int lr = c >> 3;
      int part = (c & 7) ^ (lr & 7);
      int rg = m0 + half * 128 + lr; if (rg > 10879) rg = 10879;
      async_copy16(A + (size_t)rg * 1024 + kc + part * 8,
                   lds + buf * 16384 + (half * 1024 + ii * 512 + w * 64) * 8);
    }
  };
  // stage one B half-tile (128 rows x 64 k): 2 loads/thread
  auto stageB = [&](int buf, int half, int kt) {
    int kc = (kt > 15 ? 15 : kt) * 64;
#pragma unroll
    for (int ii = 0; ii < 2; ++ii) {
      int c = ii * 512 + t;
      int lr = c >> 3;
      int part = (c & 7) ^ (lr & 7);
      async_copy16(Bm + (size_t)(n0 + half * 128 + lr) * 1024 + kc + part * 8,
                   lds + 32768 + buf * 16384 + (half * 1024 + ii * 512 + w * 64) * 8);
    }
  };

  f32x4 acc[8][4];
#pragma unroll
  for (int i = 0; i < 8; ++i)
#pragma unroll
    for (int j = 0; j < 4; ++j)
#pragma unroll
      for (int r = 0; r < 4; ++r) acc[i][j][r] = 0.f;

  auto dsA = [&](const unsigned short* Ab, int q, bf16x8 af[2][2]) {
#pragma unroll
    for (int j = 0; j < 2; ++j) {
      int row = wm2 * 128 + (2 * q + j) * 16 + col;
#pragma unroll
      for (int kq = 0; kq < 2; ++kq)
        af[j][kq] = *reinterpret_cast<const bf16x8*>(
            &Ab[(row * 8 + ((kq * 4 + quad) ^ (col & 7))) * 8]);
    }
  };
  auto dsB = [&](const unsigned short* Bbp, bf16x8 bf[4][2]) {
#pragma unroll
    for (int ni = 0; ni < 4; ++ni) {
      int row = wn2 * 64 + ni * 16 + col;
#pragma unroll
      for (int kq = 0; kq < 2; ++kq)
        bf[ni][kq] = *reinterpret_cast<const bf16x8*>(
            &Bbp[(row * 8 + ((kq * 4 + quad) ^ (col & 7))) * 8]);
    }
  };
  auto mfmaQ = [&](int q, bf16x8 af[2][2], bf16x8 bf[4][2]) {
#pragma unroll
    for (int j = 0; j < 2; ++j)
#pragma unroll
      for (int ni = 0; ni < 4; ++ni)
#pragma unroll
        for (int kq = 0; kq < 2; ++kq)
          acc[2 * q + j][ni] = __builtin_amdgcn_mfma_f32_16x16x32_bf16(
              af[j][kq], bf[ni][kq], acc[2 * q + j][ni], 0, 0, 0);
  };

  const unsigned short* A0 = lds;
  const unsigned short* A1 = lds + 16384;
  const unsigned short* B0 = lds + 32768;
  const unsigned short* B1 = lds + 49152;

  // prologue: A(0)->A0, B(0)->B0, B(1)->B1 (12 loads/thread); wait first 8, barrier.
  stageA(0, 0, 0); stageA(0, 1, 0);
  stageB(0, 0, 0); stageB(0, 1, 0);
  stageB(1, 0, 1); stageB(1, 1, 1);
  asm volatile("s_waitcnt vmcnt(4)" ::: "memory");   // A(0),B(0) landed; B(1) in flight
  SCHED0;
  BARRIER;

  for (int i = 0; i < 8; ++i) {
    const int t1k = 2 * i + 1;
    const int ts0 = 2 * i + 2;    // even next -> buf0 (clamped in stage)
    const int ts1 = 2 * i + 3;    // odd next  -> buf1
    bf16x8 bf[4][2], af[2][2];

    // ---- p0: read B(2i),A(2i)q0; stage A(2i+1) ----
    dsB(B0, bf); dsA(A0, 0, af);
    stageA(1, 0, t1k); stageA(1, 1, t1k);
    BARRIER; LGKM0;
    PRIO1; mfmaQ(0, af, bf); PRIO0;
    BARRIER;
    // ---- p1 ----
    dsA(A0, 1, af);
    stageB(0, 0, ts0);
    BARRIER; LGKM0;
    PRIO1; mfmaQ(1, af, bf); PRIO0;
    BARRIER;
    // ---- p2 ----
    dsA(A0, 2, af);
    stageB(0, 1, ts0);
    BARRIER; LGKM0;
    PRIO1; mfmaQ(2, af, bf); PRIO0;
    BARRIER;
    // ---- p3: producer-side wait: B(2i+1),A(2i+1) landed before p4 reads ----
    dsA(A0, 3, af);
    BARRIER; LGKM0;
    PRIO1; mfmaQ(3, af, bf); PRIO0;
    asm volatile("s_waitcnt vmcnt(4)" ::: "memory");
    SCHED0;
    BARRIER;
    // ---- p4: read B(2i+1),A(2i+1)q0; stage A(2i+2)h0 ----
    dsB(B1, bf); dsA(A1, 0, af);
    stageA(0, 0, ts0);
    BARRIER; LGKM0;
    PRIO1; mfmaQ(0, af, bf); PRIO0;
    BARRIER;
    // ---- p5 ----
    dsA(A1, 1, af);
    stageA(0, 1, ts0);
    BARRIER; LGKM0;
    PRIO1; mfmaQ(1, af, bf); PRIO0;
    BARRIER;
    // ---- p6 ----
    dsA(A1, 2, af);
    stageB(1, 0, ts1);
    BARRIER; LGKM0;
    PRIO1; mfmaQ(2, af, bf); PRIO0;
    BARRIER;
    // ---- p7: producer-side wait: B(2i+2),A(2i+2) landed before next p0 reads ----
    dsA(A1, 3, af);
    stageB(1, 1, ts1);
    BARRIER; LGKM0;
    PRIO1; mfmaQ(3, af, bf); PRIO0;
    asm volatile("s_waitcnt vmcnt(4)" ::: "memory");
    SCHED0;
    BARRIER;
  }
  // acc indexed by output quadrant (2q+j), not K-tile -> both K-tiles accumulate. ✓

  // ---- fused epilogue (same algebra as verified version; wave owns one head) ----
  const int nbase = n0 + wn2 * 64;
  const int field = nbase >> 10;          // wave-uniform
  const int h = (nbase >> 6) & 15;

  if (field < 2) {
    float scl[8][4];
    if (field == 1) {                     // k: per-row 1/||k|| across the 16 col-lanes
#pragma unroll
      for (int mi = 0; mi < 8; ++mi)
#pragma unroll
        for (int r = 0; r < 4; ++r) {
          float s = 0.f;
#pragma unroll
          for (int ni = 0; ni < 4; ++ni) s += acc[mi][ni][r] * acc[mi][ni][r];
          s += __shfl_xor(s, 1); s += __shfl_xor(s, 2);
          s += __shfl_xor(s, 4); s += __shfl_xor(s, 8);
          scl[mi][r] = 1.f / fmaxf(sqrtf(s), 1e-12f);
        }
    }
    unsigned short* dst0 = (field == 0) ? qn : kn;
#pragma unroll
    for (int ni = 0; ni < 4; ++ni) {
      const int d = ni * 16 + col;
      const float bv = (field == 0) ? qb[h * 64 + d] : 0.f;
#pragma unroll
      for (int mi = 0; mi < 8; ++mi)
#pragma unroll
        for (int r = 0; r < 4; ++r) {
          int gm = m0 + wm2 * 128 + mi * 16 + quad * 4 + r;
          if (gm < 10880) {
            int b = gm / 680, l = gm - b * 680;
            float v = (field == 0) ? (acc[mi][ni][r] + bv) : (acc[mi][ni][r] * scl[mi][r]);
            dst0[((size_t)(b * Hh + h) * Ll + l) * 64 + d] = f32_bf16(v);
          }
        }
    }
  } else {                                // v: transposed, segment-padded (table lookup)
#pragma unroll
    for (int mi = 0; mi < 8; ++mi) {
      int pl4[4], bb4[4], ok4[4];
#pragma unroll
      for (int r = 0; r < 4; ++r) {
        int gm = m0 + wm2 * 128 + mi * 16 + quad * 4 + r;
        ok4[r] = gm < 10880;
        int gmc = ok4[r] ? gm : 0;
        int b = gmc / 680, l = gmc - b * 680;
        pl4[r] = c_plt.v[l];
        bb4[r] = b;
      }
#pragma unroll
      for (int ni = 0; ni < 4; ++ni) {
        const int d = ni * 16 + col;
        const float bv = vb[h * 64 + d];
#pragma unroll
        for (int r = 0; r < 4; ++r)
          if (ok4[r])
            vtb[((size_t)(bb4[r] * Hh + h) * 64 + d) * LPAD + pl4[r]] =
                f32_bf16(acc[mi][ni][r] + bv);
      }
    }
  }
}

// ---------------- plain B^T GEMM (proj), f32 out ----------------
__global__ __launch_bounds__(256) void gemm_bt(const unsigned short* __restrict__ A,
                                               const unsigned short* __restrict__ Bm,
                                               const float* __restrict__ bias,
                                               float* __restrict__ outp,
                                               int M, int N, int K) {
  __shared__ __align__(16) unsigned short As[128 * 64];
  __shared__ __align__(16) unsigned short Bs[128 * 64];
  const int t = threadIdx.x;
  const int lane = t & 63, w = t >> 6;
  const int col = lane & 15, quad = lane >> 4;
  const int wm = (w & 1) * 64, wn = (w >> 1) * 64;
  const int m0 = blockIdx.y * 128, n0 = blockIdx.x * 128;

  f32x4 acc[4][4];
#pragma unroll
  for (int i = 0; i < 4; ++i)
#pragma unroll
    for (int j = 0; j < 4; ++j)
#pragma unroll
      for (int r = 0; r < 4; ++r) acc[i][j][r] = 0.f;

  const int cbase = w * 256 + lane;
  for (int k0 = 0; k0 < K; k0 += 64) {
    __syncthreads();
#pragma unroll
    for (int i = 0; i < 4; ++i) {
      int c = cbase + i * 64;
      int r = c >> 3;
      int part = (c & 7) ^ (r & 7);
      async_copy16(A + (size_t)(m0 + r) * K + k0 + part * 8, As + (w * 256 + i * 64) * 8);
      async_copy16(Bm + (size_t)(n0 + r) * K + k0 + part * 8, Bs + (w * 256 + i * 64) * 8);
    }
    __syncthreads();
#pragma unroll
    for (int kk = 0; kk < 64; kk += 32) {
      const int p = (kk >> 3) + quad;
      bf16x8 af[4], bfr[4];
#pragma unroll
      for (int mi = 0; mi < 4; ++mi) {
        int row = wm + mi * 16 + col;
        af[mi] = *reinterpret_cast<const bf16x8*>(&As[(row * 8 + (p ^ (col & 7))) * 8]);
      }
#pragma unroll
      for (int ni = 0; ni < 4; ++ni) {
        int row = wn + ni * 16 + col;
        bfr[ni] = *reinterpret_cast<const bf16x8*>(&Bs[(row * 8 + (p ^ (col & 7))) * 8]);
      }
#pragma unroll
      for (int mi = 0; mi < 4; ++mi)
#pragma unroll
        for (int ni = 0; ni < 4; ++ni)
          acc[mi][ni] = __builtin_amdgcn_mfma_f32_16x16x32_bf16(af[mi], bfr[ni], acc[mi][ni], 0, 0, 0);
    }
  }
#pragma unroll
  for (int mi = 0; mi < 4; ++mi)
#pragma unroll
    for (int ni = 0; ni < 4; ++ni) {
      int gn = n0 + wn + ni * 16 + col;
      float bv = bias[gn];
#pragma unroll
      for (int r = 0; r < 4; ++r) {
        int gm = m0 + wm + mi * 16 + quad * 4 + r;
        outp[(size_t)gm * N + gn] = acc[mi][ni][r] + bv;
      }
    }
}

// ---------------- attention v5: sized staging + XCD-grouped slots ----------------
__global__ __launch_bounds__(256) void attn_kernel(const unsigned short* __restrict__ qn,
                                                   const unsigned short* __restrict__ kn,
                                                   const unsigned short* __restrict__ vtb,
                                                   const float* __restrict__ slog,
                                                   unsigned short* __restrict__ outb) {
  __shared__ __align__(16) unsigned short Ks[128 * 64];   // chunk(row,cc) at row*8 + (cc^(row&7))
  __shared__ __align__(16) unsigned short Vs[64 * 128];   // chunk(d,jc)  at d*16 + (jc^(d&15))
  __shared__ __align__(16) unsigned short Ps[4 * 16 * 132];

  const int t = threadIdx.x;
  const int lane = t & 63, w = t >> 6;
  const int col = lane & 15, quad = lane >> 4;
  const int wi = blockIdx.x >> 8, bh = blockIdx.x & 255;
  const int h = bh & 15;
  const int seg = c_seg[wi];
  const int start = c_start2[seg], ln = c_len[seg], ps = c_ps[seg];
  const int njt = (ln + 15) >> 4;
  const int nchunk = (njt + 7) >> 3;
  const int qt = c_tile0[wi] + w;
  const bool qvalid = qt < njt;
  const float smul = __expf(fminf(slog[h], 4.6051701859880914f));

  // ---- Q fragment + in-register l2norm*scale ----
  const int qi = qt * 16 + col;
  const unsigned short* qrow = qn + ((size_t)bh * Ll + start + qi) * 64;
  bf16x8 qf0 = *reinterpret_cast<const bf16x8*>(qrow + quad * 8);
  bf16x8 qf1 = *reinterpret_cast<const bf16x8*>(qrow + 32 + quad * 8);
  {
    float ss = 0.f;
#pragma unroll
    for (int e = 0; e < 8; ++e) {
      float f0 = bf16_f32((unsigned short)qf0[e]), f1 = bf16_f32((unsigned short)qf1[e]);
      ss += f0 * f0 + f1 * f1;
    }
    ss += __shfl_xor(ss, 16);
    ss += __shfl_xor(ss, 32);
    const float qsc = smul / fmaxf(sqrtf(ss), 1e-12f);
#pragma unroll
    for (int e = 0; e < 8; ++e) {
      qf0[e] = (short)f32_bf16(bf16_f32((unsigned short)qf0[e]) * qsc);
      qf1[e] = (short)f32_bf16(bf16_f32((unsigned short)qf1[e]) * qsc);
    }
  }

  f32x4 o[4];
#pragma unroll
  for (int nt = 0; nt < 4; ++nt)
#pragma unroll
    for (int r = 0; r < 4; ++r) o[nt][r] = 0.f;
  float m4[4] = {-1e30f, -1e30f, -1e30f, -1e30f};
  float l4[4] = {0.f, 0.f, 0.f, 0.f};

  const int jc_t = (t & 15) ^ (t >> 4);   // thread-fixed V j-chunk

  for (int ch = 0; ch < nchunk; ++ch) {
    const int jbase = ch * 128;
    const int jtc = (njt - ch * 8 > 8) ? 8 : (njt - ch * 8);
    const int jtcp = (jtc + 1) & ~1;
    const int rowsK = jtc * 16;
    const int jcmax = jtcp * 2;
    __syncthreads();   // previous chunk's LDS reads done

    // ---- stage K rows (rowsK x 64d) ----
#pragma unroll
    for (int i = 0; i < 4; ++i) {
      int c = i * 256 + w * 64 + lane;
      int jr = c >> 3;
      if (jr < rowsK) {
        int cc = (c & 7) ^ (jr & 7);
        async_copy16(kn + ((size_t)bh * Ll + start + jbase + jr) * 64 + cc * 8,
                     Ks + (i * 256 + w * 64) * 8);
      }
    }
    // ---- stage V^T (64d x jcmax*8 j) ----
    if (jc_t < jcmax) {
#pragma unroll
      for (int i = 0; i < 4; ++i) {
        int d = i * 16 + (t >> 4);
        async_copy16(vtb + ((size_t)bh * 64 + d) * LPAD + ps + jbase + jc_t * 8,
                     Vs + (i * 256 + w * 64) * 8);
      }
    }
    __syncthreads();

    // ---- S = Q K^T ----
    f32x4 sf[8];
#pragma unroll
    for (int jt = 0; jt < 8; ++jt) {
      if (jt >= jtcp) continue;
      f32x4 s;
#pragma unroll
      for (int r = 0; r < 4; ++r) s[r] = 0.f;
      if (jt < jtc) {
        int jrow = jt * 16 + col;
        bf16x8 k0 = *reinterpret_cast<const bf16x8*>(&Ks[(jrow * 8 + (quad ^ (jrow & 7))) * 8]);
        bf16x8 k1 = *reinterpret_cast<const bf16x8*>(&Ks[(jrow * 8 + ((4 + quad) ^ (jrow & 7))) * 8]);
        s = __builtin_amdgcn_mfma_f32_16x16x32_bf16(qf0, k0, s, 0, 0, 0);
        s = __builtin_amdgcn_mfma_f32_16x16x32_bf16(qf1, k1, s, 0, 0, 0);
      }
      if (jbase + jt * 16 + col >= ln) {
#pragma unroll
        for (int r = 0; r < 4; ++r) s[r] = -1e30f;
      }
      sf[jt] = s;
    }
    // ---- online softmax ----
    float mc[4];
#pragma unroll
    for (int r = 0; r < 4; ++r) mc[r] = sf[0][r];
#pragma unroll
    for (int jt = 1; jt < 8; ++jt) {
      if (jt >= jtcp) continue;
#pragma unroll
      for (int r = 0; r < 4; ++r) mc[r] = fmaxf(mc[r], sf[jt][r]);
    }
#pragma unroll
    for (int mask = 1; mask <= 8; mask <<= 1)
#pragma unroll
      for (int r = 0; r < 4; ++r) mc[r] = fmaxf(mc[r], __shfl_xor(mc[r], mask));
    float alpha[4];
#pragma unroll
    for (int r = 0; r < 4; ++r) {
      float mn = fmaxf(m4[r], mc[r]);
      alpha[r] = __expf(m4[r] - mn);
      m4[r] = mn;
    }
    float ls[4] = {0.f, 0.f, 0.f, 0.f};
#pragma unroll
    for (int jt = 0; jt < 8; ++jt) {
      if (jt >= jtcp) continue;
#pragma unroll
      for (int r = 0; r < 4; ++r) {
        float pv = __expf(sf[jt][r] - m4[r]);
        ls[r] += pv;
        Ps[(w * 16 + quad * 4 + r) * 132 + jt * 16 + col] = f32_bf16(pv);
      }
    }
#pragma unroll
    for (int mask = 1; mask <= 8; mask <<= 1)
#pragma unroll
      for (int r = 0; r < 4; ++r) ls[r] += __shfl_xor(ls[r], mask);
#pragma unroll
    for (int r = 0; r < 4; ++r) l4[r] = l4[r] * alpha[r] + ls[r];
#pragma unroll
    for (int nt = 0; nt < 4; ++nt)
#pragma unroll
      for (int r = 0; r < 4; ++r) o[nt][r] *= alpha[r];

    // ---- O += P V ----
#pragma unroll
    for (int kk2 = 0; kk2 < 4; ++kk2) {
      if (kk2 >= (jtcp >> 1)) continue;
      bf16x8 pf = *reinterpret_cast<const bf16x8*>(&Ps[(w * 16 + col) * 132 + kk2 * 32 + quad * 8]);
#pragma unroll
      for (int nt = 0; nt < 4; ++nt) {
        int d = nt * 16 + col;
        int slot = (kk2 * 4 + quad) ^ (d & 15);
        bf16x8 vf = *reinterpret_cast<const bf16x8*>(&Vs[(d * 16 + slot) * 8]);
        o[nt] = __builtin_amdgcn_mfma_f32_16x16x32_bf16(pf, vf, o[nt], 0, 0, 0);
      }
    }
  }

  if (qvalid) {
    float inv[4];
#pragma unroll
    for (int r = 0; r < 4; ++r) inv[r] = 1.f / l4[r];
    const int b = bh >> 4;
#pragma unroll
    for (int nt = 0; nt < 4; ++nt)
#pragma unroll
      for (int r = 0; r < 4; ++r) {
        int ri = qt * 16 + quad * 4 + r;
        if (ri < ln) {
          size_t off = ((size_t)b * Ll + start + ri) * Cc + h * 64 + nt * 16 + col;
          outb[off] = f32_bf16(o[nt][r] * inv[r]);
        }
      }
  }
}

extern "C" void kernel_launch(void* const* d_in, const int* in_sizes, int n_in,
                              void* d_out, int out_size, void* d_ws, size_t ws_size,
                              hipStream_t stream) {
  const float* x     = (const float*)d_in[0];
  const float* wqkv  = (const float*)d_in[2];
  const float* qbias = (const float*)d_in[3];
  const float* vbias = (const float*)d_in[4];
  const float* slog  = (const float*)d_in[5];
  const float* wproj = (const float*)d_in[6];
  const float* pbias = (const float*)d_in[7];
  float* out = (float*)d_out;

  const size_t nX  = (size_t)Bb * Ll * Cc;      // 11,141,120
  const size_t nWq = (size_t)3 * Cc * Cc;       // 3,145,728
  const size_t nWp = (size_t)Cc * Cc;           // 1,048,576
  const size_t nVt = (size_t)Bb * Hh * 64 * LPAD;

  char* p = (char*)d_ws;
  unsigned short* xb     = (unsigned short*)p;  p += nX * 2;
  unsigned short* wqkvb  = (unsigned short*)p;  p += nWq * 2;
  unsigned short* wprojb = (unsigned short*)p;  p += nWp * 2;
  unsigned short* qn     = (unsigned short*)p;  p += nX * 2;
  unsigned short* kn     = (unsigned short*)p;  p += nX * 2;
  unsigned short* vtb    = (unsigned short*)p;  p += nVt * 2;
  unsigned short* attn   = xb;  // reuse: xb dead after gemm_qkv

  conv_kernel<<<(int)(nX / 1024), 256, 0, stream>>>(x, xb, (int)nX);
  conv_kernel<<<(int)(nWq / 1024), 256, 0, stream>>>(wqkv, wqkvb, (int)nWq);
  conv_kernel<<<(int)(nWp / 1024), 256, 0, stream>>>(wproj, wprojb, (int)nWp);

  gemm_qkv<<<dim3(12, 43), 512, 0, stream>>>(xb, wqkvb, qbias, vbias, qn, kn, vtb);
  attn_kernel<<<Bb * Hh * 16, 256, 0, stream>>>(qn, kn, vtb, slog, attn);
  gemm_bt<<<dim3(8, 85), 256, 0, stream>>>(attn, wprojb, pbias, out, 10880, 1024, 1024);
}

// Round 10
// 328.732 us; speedup vs baseline: 1.0664x; 1.0664x over previous
//
#include <hip/hip_runtime.h>

typedef __attribute__((ext_vector_type(8))) short bf16x8;
typedef __attribute__((ext_vector_type(4))) float f32x4;

#define Hh   16
#define Ll   680
#define Cc   1024
#define Bb   16
#define NSEG 10
#define LPAD 720   // padded per-segment V length (each segment start 8-aligned)

__device__ __forceinline__ unsigned short f32_bf16(float f) {
  union { float f; unsigned int u; } x; x.f = f;
  unsigned int r = x.u + 0x7FFFu + ((x.u >> 16) & 1u);   // RNE
  return (unsigned short)(r >> 16);
}
__device__ __forceinline__ float bf16_f32(unsigned short u) {
  union { unsigned int u; float f; } x; x.u = ((unsigned int)u) << 16;
  return x.f;
}

__device__ __forceinline__ void async_copy16(const unsigned short* g, unsigned short* l) {
  __builtin_amdgcn_global_load_lds(
      (const __attribute__((address_space(1))) unsigned int*)g,
      (__attribute__((address_space(3))) unsigned int*)l, 16, 0, 0);
}

// segment tables (patch_nums are compile-time constants)
__device__ __constant__ int c_start2[11] = {0,1,5,14,30,55,91,155,255,424,680};
__device__ __constant__ int c_ps[NSEG]   = {0,8,16,32,48,80,120,184,288,464};
__device__ __constant__ int c_seg[16]    = {0,1,2,3,4,5,6,7,7,8,8,8,9,9,9,9};
__device__ __constant__ int c_tile0[16]  = {0,0,0,0,0,0,0,0,4,0,4,8,0,4,8,12};
__device__ __constant__ int c_len[NSEG]  = {1,4,9,16,25,36,64,100,169,256};

// compile-time l -> padded-l table (kills the per-element segment search)
struct PlTab { unsigned short v[Ll]; };
constexpr PlTab make_pl() {
  PlTab t{};
  int starts[11] = {0,1,5,14,30,55,91,155,255,424,680};
  int ps[10]     = {0,8,16,32,48,80,120,184,288,464};
  for (int s = 0; s < 10; ++s)
    for (int l = starts[s]; l < starts[s + 1]; ++l)
      t.v[l] = (unsigned short)(l - starts[s] + ps[s]);
  return t;
}
__device__ __constant__ PlTab c_plt = make_pl();

// ---------------- elementwise f32 -> bf16 cast ----------------
__global__ __launch_bounds__(256) void conv_kernel(const float* __restrict__ src,
                                                   unsigned short* __restrict__ dst, int n) {
  int i = (blockIdx.x * 256 + threadIdx.x) * 4;
  if (i + 3 < n) {
    float4 v = *reinterpret_cast<const float4*>(src + i);
    ushort4 o;
    o.x = f32_bf16(v.x); o.y = f32_bf16(v.y); o.z = f32_bf16(v.z); o.w = f32_bf16(v.w);
    *reinterpret_cast<ushort4*>(dst + i) = o;
  }
}

// ---------------- QKV GEMM (R4 best-measured: 128x256 tile, half-tile ring) ----------------
__global__ __launch_bounds__(512, 2) void gemm_qkv(const unsigned short* __restrict__ A,
                                                   const unsigned short* __restrict__ Bm,
                                                   const float* __restrict__ qb,
                                                   const float* __restrict__ vb,
                                                   unsigned short* __restrict__ qn,
                                                   unsigned short* __restrict__ kn,
                                                   unsigned short* __restrict__ vtb) {
  // A slots: 6 x 4096 shorts (48KB) at [0, 24576); B slots: 6 x 8192 shorts (96KB) after.
  __shared__ __align__(16) unsigned short lds[73728];
  const int t = threadIdx.x;
  const int lane = t & 63, w = t >> 6;
  const int col = lane & 15, quad = lane >> 4;
  const int wn = (w >> 1) * 64;
  const int m0 = blockIdx.y * 128, n0 = blockIdx.x * 256;
  const int bhs = wn >> 7;                       // wave's B half (0 or 1)

  // stage one A half-tile (64 rows x 64 k = 8KB): 1 load/thread
  auto stageA = [&](int d3, int hs, int k0) {
    int kc = k0 > 960 ? 960 : k0;                // tail clamp (staged-but-never-read)
    int r = t >> 3;                              // 0..63
    int part = (t & 7) ^ (r & 7);
    async_copy16(A + (size_t)(m0 + hs * 64 + r) * 1024 + kc + part * 8,
                 lds + (d3 * 2 + hs) * 4096 + w * 512);
  };
  // stage one B half-tile (128 rows x 64 k = 16KB): 2 loads/thread
  auto stageB = [&](int d3, int hs, int k0) {
    int kc = k0 > 960 ? 960 : k0;
#pragma unroll
    for (int i = 0; i < 2; ++i) {
      int c = i * 512 + t;
      int r = c >> 3;                            // 0..127
      int part = (c & 7) ^ (r & 7);
      async_copy16(Bm + (size_t)(n0 + hs * 128 + r) * 1024 + kc + part * 8,
                   lds + 24576 + (d3 * 2 + hs) * 8192 + (i * 512 + w * 64) * 8);
    }
  };

  f32x4 acc[4][4];
#pragma unroll
  for (int i = 0; i < 4; ++i)
#pragma unroll
    for (int j = 0; j < 4; ++j)
#pragma unroll
      for (int r = 0; r < 4; ++r) acc[i][j][r] = 0.f;

  // prologue: tiles 0,1 full + {Bh0,Ah0} of tile 2 = 15 loads/thread
#pragma unroll
  for (int tt = 0; tt < 2; ++tt) {
    stageB(tt, 0, tt * 64); stageA(tt, 0, tt * 64);
    stageB(tt, 1, tt * 64); stageA(tt, 1, tt * 64);
  }
  stageB(2, 0, 128); stageA(2, 0, 128);
  asm volatile("s_waitcnt vmcnt(9)" ::: "memory");   // tile 0 landed; 9 in flight
  __builtin_amdgcn_s_barrier();
  __builtin_amdgcn_sched_barrier(0);

  int bsel = 0;
  for (int tt = 0; tt < 16; ++tt) {
    const int b  = bsel;                          // this tile's buf
    const int b2 = (bsel + 2 >= 3) ? bsel - 1 : bsel + 2;   // (tt+2)%3
    const unsigned short* As0 = lds + (b * 2 + 0) * 4096;
    const unsigned short* As1 = lds + (b * 2 + 1) * 4096;
    const unsigned short* Bs  = lds + 24576 + (b * 2 + bhs) * 8192;
    bf16x8 bfr[4][2], af[2][2];

    // ===== phase 0: read B(all) + A-half0 frags; stage Bh1,Ah1(tt+2); 16 MFMA =====
#pragma unroll
    for (int nf = 0; nf < 4; ++nf) {
      int rb = (wn & 64) + nf * 16 + col;
#pragma unroll
      for (int kq = 0; kq < 2; ++kq)
        bfr[nf][kq] = *reinterpret_cast<const bf16x8*>(
            &Bs[(rb * 8 + ((kq * 4 + quad) ^ (col & 7))) * 8]);
    }
#pragma unroll
    for (int j = 0; j < 2; ++j) {
      int ri = (w & 1) * 32 + j * 16 + col;
#pragma unroll
      for (int kq = 0; kq < 2; ++kq)
        af[j][kq] = *reinterpret_cast<const bf16x8*>(
            &As0[(ri * 8 + ((kq * 4 + quad) ^ (col & 7))) * 8]);
    }
    stageB(b2, 1, (tt + 2) * 64);
    stageA(b2, 1, (tt + 2) * 64);
    __builtin_amdgcn_s_barrier();
    __builtin_amdgcn_s_setprio(1);
#pragma unroll
    for (int j = 0; j < 2; ++j)
#pragma unroll
      for (int nf = 0; nf < 4; ++nf)
#pragma unroll
        for (int kq = 0; kq < 2; ++kq)
          acc[j][nf] = __builtin_amdgcn_mfma_f32_16x16x32_bf16(af[j][kq], bfr[nf][kq],
                                                               acc[j][nf], 0, 0, 0);
    __builtin_amdgcn_s_setprio(0);
    __builtin_amdgcn_sched_barrier(0);
    asm volatile("s_waitcnt vmcnt(6)" ::: "memory");   // Ah1/Bh1(tt) landed for phase 1
    __builtin_amdgcn_s_barrier();
    __builtin_amdgcn_sched_barrier(0);

    // ===== phase 1: read A-half1 frags (B held in regs); stage Bh0,Ah0(tt+3); 16 MFMA =====
#pragma unroll
    for (int j = 0; j < 2; ++j) {
      int ri = (w & 1) * 32 + j * 16 + col;
#pragma unroll
      for (int kq = 0; kq < 2; ++kq)
        af[j][kq] = *reinterpret_cast<const bf16x8*>(
            &As1[(ri * 8 + ((kq * 4 + quad) ^ (col & 7))) * 8]);
    }
    stageB(b, 0, (tt + 3) * 64);                 // (tt+3)%3 == b; B(b)/Ah0(b) freed at ph0 bar
    stageA(b, 0, (tt + 3) * 64);
    __builtin_amdgcn_s_barrier();
    __builtin_amdgcn_s_setprio(1);
#pragma unroll
    for (int j = 0; j < 2; ++j)
#pragma unroll
      for (int nf = 0; nf < 4; ++nf)
#pragma unroll
        for (int kq = 0; kq < 2; ++kq)
          acc[2 + j][nf] = __builtin_amdgcn_mfma_f32_16x16x32_bf16(af[j][kq], bfr[nf][kq],
                                                                   acc[2 + j][nf], 0, 0, 0);
    __builtin_amdgcn_s_setprio(0);
    __builtin_amdgcn_sched_barrier(0);
    asm volatile("s_waitcnt vmcnt(9)" ::: "memory");   // B/Ah0(tt+1) landed for next ph0
    __builtin_amdgcn_s_barrier();
    __builtin_amdgcn_sched_barrier(0);

    bsel = (bsel == 2) ? 0 : bsel + 1;
  }

  // ---- fused epilogue (same algebra; row mapping remapped for the half-split) ----
  const int nbase = n0 + wn;
  const int field = nbase >> 10;          // wave-uniform
  const int h = (nbase >> 6) & 15;

  if (field < 2) {
    float scl[4][4];
    if (field == 1) {                     // k: per-row 1/||k|| across the 16 col-lanes
#pragma unroll
      for (int mi = 0; mi < 4; ++mi)
#pragma unroll
        for (int r = 0; r < 4; ++r) {
          float s = 0.f;
#pragma unroll
          for (int ni = 0; ni < 4; ++ni) s += acc[mi][ni][r] * acc[mi][ni][r];
          s += __shfl_xor(s, 1); s += __shfl_xor(s, 2);
          s += __shfl_xor(s, 4); s += __shfl_xor(s, 8);
          scl[mi][r] = 1.f / fmaxf(sqrtf(s), 1e-12f);
        }
    }
    unsigned short* dst0 = (field == 0) ? qn : kn;
#pragma unroll
    for (int ni = 0; ni < 4; ++ni) {
      const int d = ni * 16 + col;
      const float bv = (field == 0) ? qb[h * 64 + d] : 0.f;
#pragma unroll
      for (int mi = 0; mi < 4; ++mi)
#pragma unroll
        for (int r = 0; r < 4; ++r) {
          int gm = m0 + (mi >> 1) * 64 + (w & 1) * 32 + (mi & 1) * 16 + quad * 4 + r;
          int b = gm / 680, l = gm - b * 680;
          float v = (field == 0) ? (acc[mi][ni][r] + bv) : (acc[mi][ni][r] * scl[mi][r]);
          dst0[((size_t)(b * Hh + h) * Ll + l) * 64 + d] = f32_bf16(v);
        }
    }
  } else {                                // v: transposed, segment-padded (table lookup)
#pragma unroll
    for (int mi = 0; mi < 4; ++mi) {
      int pl4[4], bb4[4];
#pragma unroll
      for (int r = 0; r < 4; ++r) {
        int gm = m0 + (mi >> 1) * 64 + (w & 1) * 32 + (mi & 1) * 16 + quad * 4 + r;
        int b = gm / 680, l = gm - b * 680;
        pl4[r] = c_plt.v[l];
        bb4[r] = b;
      }
#pragma unroll
      for (int ni = 0; ni < 4; ++ni) {
        const int d = ni * 16 + col;
        const float bv = vb[h * 64 + d];
#pragma unroll
        for (int r = 0; r < 4; ++r)
          vtb[((size_t)(bb4[r] * Hh + h) * 64 + d) * LPAD + pl4[r]] =
              f32_bf16(acc[mi][ni][r] + bv);
      }
    }
  }
}

// ---------------- plain B^T GEMM (proj), f32 out ----------------
__global__ __launch_bounds__(256) void gemm_bt(const unsigned short* __restrict__ A,
                                               const unsigned short* __restrict__ Bm,
                                               const float* __restrict__ bias,
                                               float* __restrict__ outp,
                                               int M, int N, int K) {
  __shared__ __align__(16) unsigned short As[128 * 64];
  __shared__ __align__(16) unsigned short Bs[128 * 64];
  const int t = threadIdx.x;
  const int lane = t & 63, w = t >> 6;
  const int col = lane & 15, quad = lane >> 4;
  const int wm = (w & 1) * 64, wn = (w >> 1) * 64;
  const int m0 = blockIdx.y * 128, n0 = blockIdx.x * 128;

  f32x4 acc[4][4];
#pragma unroll
  for (int i = 0; i < 4; ++i)
#pragma unroll
    for (int j = 0; j < 4; ++j)
#pragma unroll
      for (int r = 0; r < 4; ++r) acc[i][j][r] = 0.f;

  const int cbase = w * 256 + lane;
  for (int k0 = 0; k0 < K; k0 += 64) {
    __syncthreads();
#pragma unroll
    for (int i = 0; i < 4; ++i) {
      int c = cbase + i * 64;
      int r = c >> 3;
      int part = (c & 7) ^ (r & 7);
      async_copy16(A + (size_t)(m0 + r) * K + k0 + part * 8, As + (w * 256 + i * 64) * 8);
      async_copy16(Bm + (size_t)(n0 + r) * K + k0 + part * 8, Bs + (w * 256 + i * 64) * 8);
    }
    __syncthreads();
#pragma unroll
    for (int kk = 0; kk < 64; kk += 32) {
      const int p = (kk >> 3) + quad;
      bf16x8 af[4], bfr[4];
#pragma unroll
      for (int mi = 0; mi < 4; ++mi) {
        int row = wm + mi * 16 + col;
        af[mi] = *reinterpret_cast<const bf16x8*>(&As[(row * 8 + (p ^ (col & 7))) * 8]);
      }
#pragma unroll
      for (int ni = 0; ni < 4; ++ni) {
        int row = wn + ni * 16 + col;
        bfr[ni] = *reinterpret_cast<const bf16x8*>(&Bs[(row * 8 + (p ^ (col & 7))) * 8]);
      }
#pragma unroll
      for (int mi = 0; mi < 4; ++mi)
#pragma unroll
        for (int ni = 0; ni < 4; ++ni)
          acc[mi][ni] = __builtin_amdgcn_mfma_f32_16x16x32_bf16(af[mi], bfr[ni], acc[mi][ni], 0, 0, 0);
    }
  }
#pragma unroll
  for (int mi = 0; mi < 4; ++mi)
#pragma unroll
    for (int ni = 0; ni < 4; ++ni) {
      int gn = n0 + wn + ni * 16 + col;
      float bv = bias[gn];
#pragma unroll
      for (int r = 0; r < 4; ++r) {
        int gm = m0 + wm + mi * 16 + quad * 4 + r;
        outp[(size_t)gm * N + gn] = acc[mi][ni][r] + bv;
      }
    }
}

// ---------------- attention v6: staging-free, barrier-free ----------------
// K/V per chunk are <=32KB each and L2-resident (shared by sibling slots) -> LDS
// staging was pure overhead (guide common-mistake #7). Fragments now read DIRECTLY
// from global at the byte-identical addresses staging used to deliver:
//   k0 = kn[row*64 + quad*8], k1 = +32  (was Ks swizzle slots)
//   vf = vtb[d*LPAD + ps+jbase + (kk2*4+quad)*8]  (was Vs swizzle slots)
// Ps is wave-private (rows w*16..+15 written/read by same wave) -> NO barriers at all.
// LDS 49KB -> 17KB: 8 blocks/CU = full 32-wave occupancy (was 12 waves).
__global__ __launch_bounds__(256) void attn_kernel(const unsigned short* __restrict__ qn,
                                                   const unsigned short* __restrict__ kn,
                                                   const unsigned short* __restrict__ vtb,
                                                   const float* __restrict__ slog,
                                                   unsigned short* __restrict__ outb) {
  __shared__ __align__(16) unsigned short Ps[4 * 16 * 132];

  const int t = threadIdx.x;
  const int lane = t & 63, w = t >> 6;
  const int col = lane & 15, quad = lane >> 4;
  const int wi = blockIdx.x >> 8, bh = blockIdx.x & 255;
  const int h = bh & 15;
  const int seg = c_seg[wi];
  const int start = c_start2[seg], ln = c_len[seg], ps = c_ps[seg];
  const int njt = (ln + 15) >> 4;
  const int nchunk = (njt + 7) >> 3;
  const int qt = c_tile0[wi] + w;
  const bool qvalid = qt < njt;
  const float smul = __expf(fminf(slog[h], 4.6051701859880914f));

  // ---- Q fragment + in-register l2norm*scale ----
  const int qi = qt * 16 + col;
  const unsigned short* qrow = qn + ((size_t)bh * Ll + start + qi) * 64;
  bf16x8 qf0 = *reinterpret_cast<const bf16x8*>(qrow + quad * 8);
  bf16x8 qf1 = *reinterpret_cast<const bf16x8*>(qrow + 32 + quad * 8);
  {
    float ss = 0.f;
#pragma unroll
    for (int e = 0; e < 8; ++e) {
      float f0 = bf16_f32((unsigned short)qf0[e]), f1 = bf16_f32((unsigned short)qf1[e]);
      ss += f0 * f0 + f1 * f1;
    }
    ss += __shfl_xor(ss, 16);
    ss += __shfl_xor(ss, 32);
    const float qsc = smul / fmaxf(sqrtf(ss), 1e-12f);
#pragma unroll
    for (int e = 0; e < 8; ++e) {
      qf0[e] = (short)f32_bf16(bf16_f32((unsigned short)qf0[e]) * qsc);
      qf1[e] = (short)f32_bf16(bf16_f32((unsigned short)qf1[e]) * qsc);
    }
  }

  f32x4 o[4];
#pragma unroll
  for (int nt = 0; nt < 4; ++nt)
#pragma unroll
    for (int r = 0; r < 4; ++r) o[nt][r] = 0.f;
  float m4[4] = {-1e30f, -1e30f, -1e30f, -1e30f};
  float l4[4] = {0.f, 0.f, 0.f, 0.f};

  for (int ch = 0; ch < nchunk; ++ch) {
    const int jbase = ch * 128;
    const int jtc = (njt - ch * 8 > 8) ? 8 : (njt - ch * 8);
    const int jtcp = (jtc + 1) & ~1;
    const unsigned short* kbase = kn + ((size_t)bh * Ll + start + jbase) * 64;
    const unsigned short* vbase = vtb + (size_t)bh * 64 * LPAD + ps + jbase;

    // ---- S = Q K^T (direct global K fragment reads) ----
    f32x4 sf[8];
#pragma unroll
    for (int jt = 0; jt < 8; ++jt) {
      if (jt >= jtcp) continue;
      f32x4 s;
#pragma unroll
      for (int r = 0; r < 4; ++r) s[r] = 0.f;
      if (jt < jtc) {
        int jrow = jt * 16 + col;
        bf16x8 k0 = *reinterpret_cast<const bf16x8*>(kbase + (size_t)jrow * 64 + quad * 8);
        bf16x8 k1 = *reinterpret_cast<const bf16x8*>(kbase + (size_t)jrow * 64 + 32 + quad * 8);
        s = __builtin_amdgcn_mfma_f32_16x16x32_bf16(qf0, k0, s, 0, 0, 0);
        s = __builtin_amdgcn_mfma_f32_16x16x32_bf16(qf1, k1, s, 0, 0, 0);
      }
      if (jbase + jt * 16 + col >= ln) {
#pragma unroll
        for (int r = 0; r < 4; ++r) s[r] = -1e30f;
      }
      sf[jt] = s;
    }
    // ---- online softmax ----
    float mc[4];
#pragma unroll
    for (int r = 0; r < 4; ++r) mc[r] = sf[0][r];
#pragma unroll
    for (int jt = 1; jt < 8; ++jt) {
      if (jt >= jtcp) continue;
#pragma unroll
      for (int r = 0; r < 4; ++r) mc[r] = fmaxf(mc[r], sf[jt][r]);
    }
#pragma unroll
    for (int mask = 1; mask <= 8; mask <<= 1)
#pragma unroll
      for (int r = 0; r < 4; ++r) mc[r] = fmaxf(mc[r], __shfl_xor(mc[r], mask));
    float alpha[4];
#pragma unroll
    for (int r = 0; r < 4; ++r) {
      float mn = fmaxf(m4[r], mc[r]);
      alpha[r] = __expf(m4[r] - mn);
      m4[r] = mn;
    }
    float ls[4] = {0.f, 0.f, 0.f, 0.f};
#pragma unroll
    for (int jt = 0; jt < 8; ++jt) {
      if (jt >= jtcp) continue;
#pragma unroll
      for (int r = 0; r < 4; ++r) {
        float pv = __expf(sf[jt][r] - m4[r]);
        ls[r] += pv;
        Ps[(w * 16 + quad * 4 + r) * 132 + jt * 16 + col] = f32_bf16(pv);
      }
    }
#pragma unroll
    for (int mask = 1; mask <= 8; mask <<= 1)
#pragma unroll
      for (int r = 0; r < 4; ++r) ls[r] += __shfl_xor(ls[r], mask);
#pragma unroll
    for (int r = 0; r < 4; ++r) l4[r] = l4[r] * alpha[r] + ls[r];
#pragma unroll
    for (int nt = 0; nt < 4; ++nt)
#pragma unroll
      for (int r = 0; r < 4; ++r) o[nt][r] *= alpha[r];

    // ---- O += P V (direct global V fragment reads; Ps same-wave, compiler orders) ----
#pragma unroll
    for (int kk2 = 0; kk2 < 4; ++kk2) {
      if (kk2 >= (jtcp >> 1)) continue;
      bf16x8 pf = *reinterpret_cast<const bf16x8*>(&Ps[(w * 16 + col) * 132 + kk2 * 32 + quad * 8]);
#pragma unroll
      for (int nt = 0; nt < 4; ++nt) {
        int d = nt * 16 + col;
        bf16x8 vf = *reinterpret_cast<const bf16x8*>(
            vbase + (size_t)d * LPAD + (kk2 * 4 + quad) * 8);
        o[nt] = __builtin_amdgcn_mfma_f32_16x16x32_bf16(pf, vf, o[nt], 0, 0, 0);
      }
    }
  }

  if (qvalid) {
    float inv[4];
#pragma unroll
    for (int r = 0; r < 4; ++r) inv[r] = 1.f / l4[r];
    const int b = bh >> 4;
#pragma unroll
    for (int nt = 0; nt < 4; ++nt)
#pragma unroll
      for (int r = 0; r < 4; ++r) {
        int ri = qt * 16 + quad * 4 + r;
        if (ri < ln) {
          size_t off = ((size_t)b * Ll + start + ri) * Cc + h * 64 + nt * 16 + col;
          outb[off] = f32_bf16(o[nt][r] * inv[r]);
        }
      }
  }
}

extern "C" void kernel_launch(void* const* d_in, const int* in_sizes, int n_in,
                              void* d_out, int out_size, void* d_ws, size_t ws_size,
                              hipStream_t stream) {
  const float* x     = (const float*)d_in[0];
  const float* wqkv  = (const float*)d_in[2];
  const float* qbias = (const float*)d_in[3];
  const float* vbias = (const float*)d_in[4];
  const float* slog  = (const float*)d_in[5];
  const float* wproj = (const float*)d_in[6];
  const float* pbias = (const float*)d_in[7];
  float* out = (float*)d_out;

  const size_t nX  = (size_t)Bb * Ll * Cc;      // 11,141,120
  const size_t nWq = (size_t)3 * Cc * Cc;       // 3,145,728
  const size_t nWp = (size_t)Cc * Cc;           // 1,048,576
  const size_t nVt = (size_t)Bb * Hh * 64 * LPAD;

  char* p = (char*)d_ws;
  unsigned short* xb     = (unsigned short*)p;  p += nX * 2;
  unsigned short* wqkvb  = (unsigned short*)p;  p += nWq * 2;
  unsigned short* wprojb = (unsigned short*)p;  p += nWp * 2;
  unsigned short* qn     = (unsigned short*)p;  p += nX * 2;
  unsigned short* kn     = (unsigned short*)p;  p += nX * 2;
  unsigned short* vtb    = (unsigned short*)p;  p += nVt * 2;
  unsigned short* attn   = xb;  // reuse: xb dead after gemm_qkv

  conv_kernel<<<(int)(nX / 1024), 256, 0, stream>>>(x, xb, (int)nX);
  conv_kernel<<<(int)(nWq / 1024), 256, 0, stream>>>(wqkv, wqkvb, (int)nWq);
  conv_kernel<<<(int)(nWp / 1024), 256, 0, stream>>>(wproj, wprojb, (int)nWp);

  gemm_qkv<<<dim3(12, 85), 512, 0, stream>>>(xb, wqkvb, qbias, vbias, qn, kn, vtb);
  attn_kernel<<<Bb * Hh * 16, 256, 0, stream>>>(qn, kn, vtb, slog, attn);
  gemm_bt<<<dim3(8, 85), 256, 0, stream>>>(attn, wprojb, pbias, out, 10880, 1024, 1024);
}

// Round 13
// 318.197 us; speedup vs baseline: 1.1017x; 1.0331x over previous
//
#include <hip/hip_runtime.h>

typedef __attribute__((ext_vector_type(8))) short bf16x8;
typedef __attribute__((ext_vector_type(4))) float f32x4;

#define Hh   16
#define Ll   680
#define Cc   1024
#define Bb   16
#define NSEG 10
#define LPAD 720   // padded per-segment V length (each segment start 8-aligned)

__device__ __forceinline__ unsigned short f32_bf16(float f) {
  union { float f; unsigned int u; } x; x.f = f;
  unsigned int r = x.u + 0x7FFFu + ((x.u >> 16) & 1u);   // RNE
  return (unsigned short)(r >> 16);
}
__device__ __forceinline__ float bf16_f32(unsigned short u) {
  union { unsigned int u; float f; } x; x.u = ((unsigned int)u) << 16;
  return x.f;
}

__device__ __forceinline__ void async_copy16(const unsigned short* g, unsigned short* l) {
  __builtin_amdgcn_global_load_lds(
      (const __attribute__((address_space(1))) unsigned int*)g,
      (__attribute__((address_space(3))) unsigned int*)l, 16, 0, 0);
}

// segment tables (patch_nums are compile-time constants)
__device__ __constant__ int c_start2[11] = {0,1,5,14,30,55,91,155,255,424,680};
__device__ __constant__ int c_ps[NSEG]   = {0,8,16,32,48,80,120,184,288,464};
__device__ __constant__ int c_seg[16]    = {0,1,2,3,4,5,6,7,7,8,8,8,9,9,9,9};
__device__ __constant__ int c_tile0[16]  = {0,0,0,0,0,0,0,0,4,0,4,8,0,4,8,12};
__device__ __constant__ int c_len[NSEG]  = {1,4,9,16,25,36,64,100,169,256};

// compile-time l -> padded-l table (kills the per-element segment search)
struct PlTab { unsigned short v[Ll]; };
constexpr PlTab make_pl() {
  PlTab t{};
  int starts[11] = {0,1,5,14,30,55,91,155,255,424,680};
  int ps[10]     = {0,8,16,32,48,80,120,184,288,464};
  for (int s = 0; s < 10; ++s)
    for (int l = starts[s]; l < starts[s + 1]; ++l)
      t.v[l] = (unsigned short)(l - starts[s] + ps[s]);
  return t;
}
__device__ __constant__ PlTab c_plt = make_pl();

// ---------------- fused elementwise f32 -> bf16 cast (all three tensors, one launch) ----------------
// Regions are 1024-aligned so each thread's float4 never straddles a boundary.
__global__ __launch_bounds__(256) void conv_all(const float* __restrict__ x,
                                                const float* __restrict__ wqkv,
                                                const float* __restrict__ wproj,
                                                unsigned short* __restrict__ xb,
                                                unsigned short* __restrict__ wqkvb,
                                                unsigned short* __restrict__ wprojb) {
  const size_t n1 = (size_t)Bb * Ll * Cc;          // 11,141,120
  const size_t n2 = n1 + (size_t)3 * Cc * Cc;      // + 3,145,728
  const size_t n3 = n2 + (size_t)Cc * Cc;          // + 1,048,576
  size_t i = ((size_t)blockIdx.x * 256 + threadIdx.x) * 4;
  if (i >= n3) return;
  const float* src; unsigned short* dst; size_t off;
  if (i < n1)      { src = x;     dst = xb;     off = i; }
  else if (i < n2) { src = wqkv;  dst = wqkvb;  off = i - n1; }
  else             { src = wproj; dst = wprojb; off = i - n2; }
  float4 v = *reinterpret_cast<const float4*>(src + off);
  ushort4 o;
  o.x = f32_bf16(v.x); o.y = f32_bf16(v.y); o.z = f32_bf16(v.z); o.w = f32_bf16(v.w);
  *reinterpret_cast<ushort4*>(dst + off) = o;
}

// ---------------- QKV GEMM (R4 best-measured: 128x256 tile, half-tile ring) ----------------
__global__ __launch_bounds__(512, 2) void gemm_qkv(const unsigned short* __restrict__ A,
                                                   const unsigned short* __restrict__ Bm,
                                                   const float* __restrict__ qb,
                                                   const float* __restrict__ vb,
                                                   unsigned short* __restrict__ qn,
                                                   unsigned short* __restrict__ kn,
                                                   unsigned short* __restrict__ vtb) {
  // A slots: 6 x 4096 shorts (48KB) at [0, 24576); B slots: 6 x 8192 shorts (96KB) after.
  __shared__ __align__(16) unsigned short lds[73728];
  const int t = threadIdx.x;
  const int lane = t & 63, w = t >> 6;
  const int col = lane & 15, quad = lane >> 4;
  const int wn = (w >> 1) * 64;
  const int m0 = blockIdx.y * 128, n0 = blockIdx.x * 256;
  const int bhs = wn >> 7;                       // wave's B half (0 or 1)

  // stage one A half-tile (64 rows x 64 k = 8KB): 1 load/thread
  auto stageA = [&](int d3, int hs, int k0) {
    int kc = k0 > 960 ? 960 : k0;                // tail clamp (staged-but-never-read)
    int r = t >> 3;                              // 0..63
    int part = (t & 7) ^ (r & 7);
    async_copy16(A + (size_t)(m0 + hs * 64 + r) * 1024 + kc + part * 8,
                 lds + (d3 * 2 + hs) * 4096 + w * 512);
  };
  // stage one B half-tile (128 rows x 64 k = 16KB): 2 loads/thread
  auto stageB = [&](int d3, int hs, int k0) {
    int kc = k0 > 960 ? 960 : k0;
#pragma unroll
    for (int i = 0; i < 2; ++i) {
      int c = i * 512 + t;
      int r = c >> 3;                            // 0..127
      int part = (c & 7) ^ (r & 7);
      async_copy16(Bm + (size_t)(n0 + hs * 128 + r) * 1024 + kc + part * 8,
                   lds + 24576 + (d3 * 2 + hs) * 8192 + (i * 512 + w * 64) * 8);
    }
  };

  f32x4 acc[4][4];
#pragma unroll
  for (int i = 0; i < 4; ++i)
#pragma unroll
    for (int j = 0; j < 4; ++j)
#pragma unroll
      for (int r = 0; r < 4; ++r) acc[i][j][r] = 0.f;

  // prologue: tiles 0,1 full + {Bh0,Ah0} of tile 2 = 15 loads/thread
#pragma unroll
  for (int tt = 0; tt < 2; ++tt) {
    stageB(tt, 0, tt * 64); stageA(tt, 0, tt * 64);
    stageB(tt, 1, tt * 64); stageA(tt, 1, tt * 64);
  }
  stageB(2, 0, 128); stageA(2, 0, 128);
  asm volatile("s_waitcnt vmcnt(9)" ::: "memory");   // tile 0 landed; 9 in flight
  __builtin_amdgcn_s_barrier();
  __builtin_amdgcn_sched_barrier(0);

  int bsel = 0;
  for (int tt = 0; tt < 16; ++tt) {
    const int b  = bsel;                          // this tile's buf
    const int b2 = (bsel + 2 >= 3) ? bsel - 1 : bsel + 2;   // (tt+2)%3
    const unsigned short* As0 = lds + (b * 2 + 0) * 4096;
    const unsigned short* As1 = lds + (b * 2 + 1) * 4096;
    const unsigned short* Bs  = lds + 24576 + (b * 2 + bhs) * 8192;
    bf16x8 bfr[4][2], af[2][2];

    // ===== phase 0: read B(all) + A-half0 frags; stage Bh1,Ah1(tt+2); 16 MFMA =====
#pragma unroll
    for (int nf = 0; nf < 4; ++nf) {
      int rb = (wn & 64) + nf * 16 + col;
#pragma unroll
      for (int kq = 0; kq < 2; ++kq)
        bfr[nf][kq] = *reinterpret_cast<const bf16x8*>(
            &Bs[(rb * 8 + ((kq * 4 + quad) ^ (col & 7))) * 8]);
    }
#pragma unroll
    for (int j = 0; j < 2; ++j) {
      int ri = (w & 1) * 32 + j * 16 + col;
#pragma unroll
      for (int kq = 0; kq < 2; ++kq)
        af[j][kq] = *reinterpret_cast<const bf16x8*>(
            &As0[(ri * 8 + ((kq * 4 + quad) ^ (col & 7))) * 8]);
    }
    stageB(b2, 1, (tt + 2) * 64);
    stageA(b2, 1, (tt + 2) * 64);
    __builtin_amdgcn_s_barrier();
    __builtin_amdgcn_s_setprio(1);
#pragma unroll
    for (int j = 0; j < 2; ++j)
#pragma unroll
      for (int nf = 0; nf < 4; ++nf)
#pragma unroll
        for (int kq = 0; kq < 2; ++kq)
          acc[j][nf] = __builtin_amdgcn_mfma_f32_16x16x32_bf16(af[j][kq], bfr[nf][kq],
                                                               acc[j][nf], 0, 0, 0);
    __builtin_amdgcn_s_setprio(0);
    __builtin_amdgcn_sched_barrier(0);
    asm volatile("s_waitcnt vmcnt(6)" ::: "memory");   // Ah1/Bh1(tt) landed for phase 1
    __builtin_amdgcn_s_barrier();
    __builtin_amdgcn_sched_barrier(0);

    // ===== phase 1: read A-half1 frags (B held in regs); stage Bh0,Ah0(tt+3); 16 MFMA =====
#pragma unroll
    for (int j = 0; j < 2; ++j) {
      int ri = (w & 1) * 32 + j * 16 + col;
#pragma unroll
      for (int kq = 0; kq < 2; ++kq)
        af[j][kq] = *reinterpret_cast<const bf16x8*>(
            &As1[(ri * 8 + ((kq * 4 + quad) ^ (col & 7))) * 8]);
    }
    stageB(b, 0, (tt + 3) * 64);                 // (tt+3)%3 == b; B(b)/Ah0(b) freed at ph0 bar
    stageA(b, 0, (tt + 3) * 64);
    __builtin_amdgcn_s_barrier();
    __builtin_amdgcn_s_setprio(1);
#pragma unroll
    for (int j = 0; j < 2; ++j)
#pragma unroll
      for (int nf = 0; nf < 4; ++nf)
#pragma unroll
        for (int kq = 0; kq < 2; ++kq)
          acc[2 + j][nf] = __builtin_amdgcn_mfma_f32_16x16x32_bf16(af[j][kq], bfr[nf][kq],
                                                                   acc[2 + j][nf], 0, 0, 0);
    __builtin_amdgcn_s_setprio(0);
    __builtin_amdgcn_sched_barrier(0);
    asm volatile("s_waitcnt vmcnt(9)" ::: "memory");   // B/Ah0(tt+1) landed for next ph0
    __builtin_amdgcn_s_barrier();
    __builtin_amdgcn_sched_barrier(0);

    bsel = (bsel == 2) ? 0 : bsel + 1;
  }

  // ---- fused epilogue (same algebra; row mapping remapped for the half-split) ----
  const int nbase = n0 + wn;
  const int field = nbase >> 10;          // wave-uniform
  const int h = (nbase >> 6) & 15;

  if (field < 2) {
    float scl[4][4];
    if (field == 1) {                     // k: per-row 1/||k|| across the 16 col-lanes
#pragma unroll
      for (int mi = 0; mi < 4; ++mi)
#pragma unroll
        for (int r = 0; r < 4; ++r) {
          float s = 0.f;
#pragma unroll
          for (int ni = 0; ni < 4; ++ni) s += acc[mi][ni][r] * acc[mi][ni][r];
          s += __shfl_xor(s, 1); s += __shfl_xor(s, 2);
          s += __shfl_xor(s, 4); s += __shfl_xor(s, 8);
          scl[mi][r] = 1.f / fmaxf(sqrtf(s), 1e-12f);
        }
    }
    unsigned short* dst0 = (field == 0) ? qn : kn;
#pragma unroll
    for (int ni = 0; ni < 4; ++ni) {
      const int d = ni * 16 + col;
      const float bv = (field == 0) ? qb[h * 64 + d] : 0.f;
#pragma unroll
      for (int mi = 0; mi < 4; ++mi)
#pragma unroll
        for (int r = 0; r < 4; ++r) {
          int gm = m0 + (mi >> 1) * 64 + (w & 1) * 32 + (mi & 1) * 16 + quad * 4 + r;
          int b = gm / 680, l = gm - b * 680;
          float v = (field == 0) ? (acc[mi][ni][r] + bv) : (acc[mi][ni][r] * scl[mi][r]);
          dst0[((size_t)(b * Hh + h) * Ll + l) * 64 + d] = f32_bf16(v);
        }
    }
  } else {                                // v: transposed, segment-padded (table lookup)
#pragma unroll
    for (int mi = 0; mi < 4; ++mi) {
      int pl4[4], bb4[4];
#pragma unroll
      for (int r = 0; r < 4; ++r) {
        int gm = m0 + (mi >> 1) * 64 + (w & 1) * 32 + (mi & 1) * 16 + quad * 4 + r;
        int b = gm / 680, l = gm - b * 680;
        pl4[r] = c_plt.v[l];
        bb4[r] = b;
      }
#pragma unroll
      for (int ni = 0; ni < 4; ++ni) {
        const int d = ni * 16 + col;
        const float bv = vb[h * 64 + d];
#pragma unroll
        for (int r = 0; r < 4; ++r)
          vtb[((size_t)(bb4[r] * Hh + h) * 64 + d) * LPAD + pl4[r]] =
              f32_bf16(acc[mi][ni][r] + bv);
      }
    }
  }
}

// ---------------- plain B^T GEMM (proj), f32 out ----------------
__global__ __launch_bounds__(256) void gemm_bt(const unsigned short* __restrict__ A,
                                               const unsigned short* __restrict__ Bm,
                                               const float* __restrict__ bias,
                                               float* __restrict__ outp,
                                               int M, int N, int K) {
  __shared__ __align__(16) unsigned short As[128 * 64];
  __shared__ __align__(16) unsigned short Bs[128 * 64];
  const int t = threadIdx.x;
  const int lane = t & 63, w = t >> 6;
  const int col = lane & 15, quad = lane >> 4;
  const int wm = (w & 1) * 64, wn = (w >> 1) * 64;
  const int m0 = blockIdx.y * 128, n0 = blockIdx.x * 128;

  f32x4 acc[4][4];
#pragma unroll
  for (int i = 0; i < 4; ++i)
#pragma unroll
    for (int j = 0; j < 4; ++j)
#pragma unroll
      for (int r = 0; r < 4; ++r) acc[i][j][r] = 0.f;

  const int cbase = w * 256 + lane;
  for (int k0 = 0; k0 < K; k0 += 64) {
    __syncthreads();
#pragma unroll
    for (int i = 0; i < 4; ++i) {
      int c = cbase + i * 64;
      int r = c >> 3;
      int part = (c & 7) ^ (r & 7);
      async_copy16(A + (size_t)(m0 + r) * K + k0 + part * 8, As + (w * 256 + i * 64) * 8);
      async_copy16(Bm + (size_t)(n0 + r) * K + k0 + part * 8, Bs + (w * 256 + i * 64) * 8);
    }
    __syncthreads();
#pragma unroll
    for (int kk = 0; kk < 64; kk += 32) {
      const int p = (kk >> 3) + quad;
      bf16x8 af[4], bfr[4];
#pragma unroll
      for (int mi = 0; mi < 4; ++mi) {
        int row = wm + mi * 16 + col;
        af[mi] = *reinterpret_cast<const bf16x8*>(&As[(row * 8 + (p ^ (col & 7))) * 8]);
      }
#pragma unroll
      for (int ni = 0; ni < 4; ++ni) {
        int row = wn + ni * 16 + col;
        bfr[ni] = *reinterpret_cast<const bf16x8*>(&Bs[(row * 8 + (p ^ (col & 7))) * 8]);
      }
#pragma unroll
      for (int mi = 0; mi < 4; ++mi)
#pragma unroll
        for (int ni = 0; ni < 4; ++ni)
          acc[mi][ni] = __builtin_amdgcn_mfma_f32_16x16x32_bf16(af[mi], bfr[ni], acc[mi][ni], 0, 0, 0);
    }
  }
#pragma unroll
  for (int mi = 0; mi < 4; ++mi)
#pragma unroll
    for (int ni = 0; ni < 4; ++ni) {
      int gn = n0 + wn + ni * 16 + col;
      float bv = bias[gn];
#pragma unroll
      for (int r = 0; r < 4; ++r) {
        int gm = m0 + wm + mi * 16 + quad * 4 + r;
        outp[(size_t)gm * N + gn] = acc[mi][ni][r] + bv;
      }
    }
}

// ---------------- attention v5 (measured best): sized staging + XCD-grouped slots ----------------
__global__ __launch_bounds__(256) void attn_kernel(const unsigned short* __restrict__ qn,
                                                   const unsigned short* __restrict__ kn,
                                                   const unsigned short* __restrict__ vtb,
                                                   const float* __restrict__ slog,
                                                   unsigned short* __restrict__ outb) {
  __shared__ __align__(16) unsigned short Ks[128 * 64];   // chunk(row,cc) at row*8 + (cc^(row&7))
  __shared__ __align__(16) unsigned short Vs[64 * 128];   // chunk(d,jc)  at d*16 + (jc^(d&15))
  __shared__ __align__(16) unsigned short Ps[4 * 16 * 132];

  const int t = threadIdx.x;
  const int lane = t & 63, w = t >> 6;
  const int col = lane & 15, quad = lane >> 4;
  const int wi = blockIdx.x >> 8, bh = blockIdx.x & 255;
  const int h = bh & 15;
  const int seg = c_seg[wi];
  const int start = c_start2[seg], ln = c_len[seg], ps = c_ps[seg];
  const int njt = (ln + 15) >> 4;
  const int nchunk = (njt + 7) >> 3;
  const int qt = c_tile0[wi] + w;
  const bool qvalid = qt < njt;
  const float smul = __expf(fminf(slog[h], 4.6051701859880914f));

  // ---- Q fragment + in-register l2norm*scale ----
  const int qi = qt * 16 + col;
  const unsigned short* qrow = qn + ((size_t)bh * Ll + start + qi) * 64;
  bf16x8 qf0 = *reinterpret_cast<const bf16x8*>(qrow + quad * 8);
  bf16x8 qf1 = *reinterpret_cast<const bf16x8*>(qrow + 32 + quad * 8);
  {
    float ss = 0.f;
#pragma unroll
    for (int e = 0; e < 8; ++e) {
      float f0 = bf16_f32((unsigned short)qf0[e]), f1 = bf16_f32((unsigned short)qf1[e]);
      ss += f0 * f0 + f1 * f1;
    }
    ss += __shfl_xor(ss, 16);
    ss += __shfl_xor(ss, 32);
    const float qsc = smul / fmaxf(sqrtf(ss), 1e-12f);
#pragma unroll
    for (int e = 0; e < 8; ++e) {
      qf0[e] = (short)f32_bf16(bf16_f32((unsigned short)qf0[e]) * qsc);
      qf1[e] = (short)f32_bf16(bf16_f32((unsigned short)qf1[e]) * qsc);
    }
  }

  f32x4 o[4];
#pragma unroll
  for (int nt = 0; nt < 4; ++nt)
#pragma unroll
    for (int r = 0; r < 4; ++r) o[nt][r] = 0.f;
  float m4[4] = {-1e30f, -1e30f, -1e30f, -1e30f};
  float l4[4] = {0.f, 0.f, 0.f, 0.f};

  const int jc_t = (t & 15) ^ (t >> 4);   // thread-fixed V j-chunk

  for (int ch = 0; ch < nchunk; ++ch) {
    const int jbase = ch * 128;
    const int jtc = (njt - ch * 8 > 8) ? 8 : (njt - ch * 8);
    const int jtcp = (jtc + 1) & ~1;
    const int rowsK = jtc * 16;
    const int jcmax = jtcp * 2;
    __syncthreads();   // previous chunk's LDS reads done

    // ---- stage K rows (rowsK x 64d) ----
#pragma unroll
    for (int i = 0; i < 4; ++i) {
      int c = i * 256 + w * 64 + lane;
      int jr = c >> 3;
      if (jr < rowsK) {
        int cc = (c & 7) ^ (jr & 7);
        async_copy16(kn + ((size_t)bh * Ll + start + jbase + jr) * 64 + cc * 8,
                     Ks + (i * 256 + w * 64) * 8);
      }
    }
    // ---- stage V^T (64d x jcmax*8 j) ----
    if (jc_t < jcmax) {
#pragma unroll
      for (int i = 0; i < 4; ++i) {
        int d = i * 16 + (t >> 4);
        async_copy16(vtb + ((size_t)bh * 64 + d) * LPAD + ps + jbase + jc_t * 8,
                     Vs + (i * 256 + w * 64) * 8);
      }
    }
    __syncthreads();

    // ---- S = Q K^T ----
    f32x4 sf[8];
#pragma unroll
    for (int jt = 0; jt < 8; ++jt) {
      if (jt >= jtcp) continue;
      f32x4 s;
#pragma unroll
      for (int r = 0; r < 4; ++r) s[r] = 0.f;
      if (jt < jtc) {
        int jrow = jt * 16 + col;
        bf16x8 k0 = *reinterpret_cast<const bf16x8*>(&Ks[(jrow * 8 + (quad ^ (jrow & 7))) * 8]);
        bf16x8 k1 = *reinterpret_cast<const bf16x8*>(&Ks[(jrow * 8 + ((4 + quad) ^ (jrow & 7))) * 8]);
        s = __builtin_amdgcn_mfma_f32_16x16x32_bf16(qf0, k0, s, 0, 0, 0);
        s = __builtin_amdgcn_mfma_f32_16x16x32_bf16(qf1, k1, s, 0, 0, 0);
      }
      if (jbase + jt * 16 + col >= ln) {
#pragma unroll
        for (int r = 0; r < 4; ++r) s[r] = -1e30f;
      }
      sf[jt] = s;
    }
    // ---- online softmax ----
    float mc[4];
#pragma unroll
    for (int r = 0; r < 4; ++r) mc[r] = sf[0][r];
#pragma unroll
    for (int jt = 1; jt < 8; ++jt) {
      if (jt >= jtcp) continue;
#pragma unroll
      for (int r = 0; r < 4; ++r) mc[r] = fmaxf(mc[r], sf[jt][r]);
    }
#pragma unroll
    for (int mask = 1; mask <= 8; mask <<= 1)
#pragma unroll
      for (int r = 0; r < 4; ++r) mc[r] = fmaxf(mc[r], __shfl_xor(mc[r], mask));
    float alpha[4];
#pragma unroll
    for (int r = 0; r < 4; ++r) {
      float mn = fmaxf(m4[r], mc[r]);
      alpha[r] = __expf(m4[r] - mn);
      m4[r] = mn;
    }
    float ls[4] = {0.f, 0.f, 0.f, 0.f};
#pragma unroll
    for (int jt = 0; jt < 8; ++jt) {
      if (jt >= jtcp) continue;
#pragma unroll
      for (int r = 0; r < 4; ++r) {
        float pv = __expf(sf[jt][r] - m4[r]);
        ls[r] += pv;
        Ps[(w * 16 + quad * 4 + r) * 132 + jt * 16 + col] = f32_bf16(pv);
      }
    }
#pragma unroll
    for (int mask = 1; mask <= 8; mask <<= 1)
#pragma unroll
      for (int r = 0; r < 4; ++r) ls[r] += __shfl_xor(ls[r], mask);
#pragma unroll
    for (int r = 0; r < 4; ++r) l4[r] = l4[r] * alpha[r] + ls[r];
#pragma unroll
    for (int nt = 0; nt < 4; ++nt)
#pragma unroll
      for (int r = 0; r < 4; ++r) o[nt][r] *= alpha[r];

    // ---- O += P V ----
#pragma unroll
    for (int kk2 = 0; kk2 < 4; ++kk2) {
      if (kk2 >= (jtcp >> 1)) continue;
      bf16x8 pf = *reinterpret_cast<const bf16x8*>(&Ps[(w * 16 + col) * 132 + kk2 * 32 + quad * 8]);
#pragma unroll
      for (int nt = 0; nt < 4; ++nt) {
        int d = nt * 16 + col;
        int slot = (kk2 * 4 + quad) ^ (d & 15);
        bf16x8 vf = *reinterpret_cast<const bf16x8*>(&Vs[(d * 16 + slot) * 8]);
        o[nt] = __builtin_amdgcn_mfma_f32_16x16x32_bf16(pf, vf, o[nt], 0, 0, 0);
      }
    }
  }

  if (qvalid) {
    float inv[4];
#pragma unroll
    for (int r = 0; r < 4; ++r) inv[r] = 1.f / l4[r];
    const int b = bh >> 4;
#pragma unroll
    for (int nt = 0; nt < 4; ++nt)
#pragma unroll
      for (int r = 0; r < 4; ++r) {
        int ri = qt * 16 + quad * 4 + r;
        if (ri < ln) {
          size_t off = ((size_t)b * Ll + start + ri) * Cc + h * 64 + nt * 16 + col;
          outb[off] = f32_bf16(o[nt][r] * inv[r]);
        }
      }
  }
}

extern "C" void kernel_launch(void* const* d_in, const int* in_sizes, int n_in,
                              void* d_out, int out_size, void* d_ws, size_t ws_size,
                              hipStream_t stream) {
  const float* x     = (const float*)d_in[0];
  const float* wqkv  = (const float*)d_in[2];
  const float* qbias = (const float*)d_in[3];
  const float* vbias = (const float*)d_in[4];
  const float* slog  = (const float*)d_in[5];
  const float* wproj = (const float*)d_in[6];
  const float* pbias = (const float*)d_in[7];
  float* out = (float*)d_out;

  const size_t nX  = (size_t)Bb * Ll * Cc;      // 11,141,120
  const size_t nWq = (size_t)3 * Cc * Cc;       // 3,145,728
  const size_t nWp = (size_t)Cc * Cc;           // 1,048,576
  const size_t nVt = (size_t)Bb * Hh * 64 * LPAD;

  char* p = (char*)d_ws;
  unsigned short* xb     = (unsigned short*)p;  p += nX * 2;
  unsigned short* wqkvb  = (unsigned short*)p;  p += nWq * 2;
  unsigned short* wprojb = (unsigned short*)p;  p += nWp * 2;
  unsigned short* qn     = (unsigned short*)p;  p += nX * 2;
  unsigned short* kn     = (unsigned short*)p;  p += nX * 2;
  unsigned short* vtb    = (unsigned short*)p;  p += nVt * 2;
  unsigned short* attn   = xb;  // reuse: xb dead after gemm_qkv

  const size_t nAll = nX + nWq + nWp;           // 15,335,424 (divisible by 1024)
  conv_all<<<(int)(nAll / 1024), 256, 0, stream>>>(x, wqkv, wproj, xb, wqkvb, wprojb);

  gemm_qkv<<<dim3(12, 85), 512, 0, stream>>>(xb, wqkvb, qbias, vbias, qn, kn, vtb);
  attn_kernel<<<Bb * Hh * 16, 256, 0, stream>>>(qn, kn, vtb, slog, attn);
  gemm_bt<<<dim3(8, 85), 256, 0, stream>>>(attn, wprojb, pbias, out, 10880, 1024, 1024);
}